// Round 3
// baseline (867.420 us; speedup 1.0000x reference)
//
#include <hip/hip_runtime.h>
#include <hip/hip_bf16.h>
#include <stdint.h>

#define NROWS 500000
#define INC 256
#define OUTC 112

typedef __attribute__((ext_vector_type(8))) short short8;
typedef __attribute__((ext_vector_type(4))) float f32x4;

static __device__ __forceinline__ uint32_t as_u32(float f) {
    union { float f; uint32_t u; } v; v.f = f; return v.u;
}
static __device__ __forceinline__ float as_f32(uint32_t u) {
    union { float f; uint32_t u; } v; v.u = u; return v.f;
}
// round-to-nearest-even bf16 (upper 16 bits); carry into exponent is correct.
static __device__ __forceinline__ unsigned short bf16_rne(float f) {
    uint32_t u = as_u32(f);
    uint32_t r = u + 0x7FFFu + ((u >> 16) & 1u);
    return (unsigned short)(r >> 16);
}
static __device__ __forceinline__ float bf16_to_f32(unsigned short h) {
    return as_f32(((uint32_t)h) << 16);
}

// ---------------- Prepass 1: convert W0 (scaled by wcat[:,0]) to bf16 hi/lo
// fragments (RNE), and build sorted relu-threshold array + ranks. ----------
// Fragment layout: Wh[(k>>3)][col][k&7] so a lane's 8 consecutive k-values
// (k = kt*32 + (lane>>4)*8 + j) for col = ct*16 + (lane&15) are one 16B load.
__global__ __launch_bounds__(256) void prep1(
    const float* __restrict__ W0, const float* __restrict__ Wn,
    const float* __restrict__ bn, const float* __restrict__ wcat,
    unsigned short* __restrict__ Wh, unsigned short* __restrict__ Wl,
    float* __restrict__ sortedTheta, int* __restrict__ rankArr)
{
    int tid = threadIdx.x;
    int gtid = blockIdx.x * 256 + tid;
    for (int idx = gtid; idx < OUTC * INC; idx += 8 * 256) {
        int col = idx >> 8;     // W0 is [112][256] row-major
        int k   = idx & 255;
        float w = W0[idx] * wcat[col * 2 + 0];   // fold wcat[:,0] into W0
        unsigned short hi = bf16_rne(w);
        float resid = w - bf16_to_f32(hi);       // exact in fp32
        unsigned short lo = bf16_rne(resid);
        int dst = (k >> 3) * (OUTC * 8) + col * 8 + (k & 7);
        Wh[dst] = hi;
        Wl[dst] = lo;
    }
    if (blockIdx.x == 0) {
        // relu(t*Wn[j]+bn[j]) crosses zero at theta_j = -bn/Wn (Wn!=0).
        __shared__ float sth[128];
        float th = INFINITY;
        if (tid < 112) {
            float w = Wn[tid];
            th = (w != 0.0f) ? (-bn[tid] / w) : INFINITY;
        }
        if (tid < 128) sth[tid] = th;
        __syncthreads();
        if (tid < 128) {
            int rank = 0;
            for (int i = 0; i < 128; ++i) {
                float o = sth[i];
                rank += (o < th) || (o == th && i < tid);  // stable rank, unique
            }
            sortedTheta[rank] = th;   // 128 entries; pads sort to the top as +inf
            rankArr[tid] = rank;
        }
    }
}

// ---------------- Prepass 2: per-segment linear tables ----------------
// For t in segment s (s = #{theta < t}):  z[k] = A[s][k]*t + C-part
// active(j): Wn>0 -> rank_j < s ; Wn<0 -> rank_j >= s ; Wn==0 -> bn>0
// Folds wcat[:,1], bc, bcat and wcat[:,0]*b0 into the C table.
__global__ __launch_bounds__(128) void prep2(
    const float* __restrict__ Wn, const float* __restrict__ bn,
    const float* __restrict__ Wc, const float* __restrict__ bc,
    const float* __restrict__ wcat, const float* __restrict__ bcat,
    const float* __restrict__ b0, const int* __restrict__ rankArr,
    float* __restrict__ Atab, float* __restrict__ Ctab)
{
    int s = blockIdx.x;      // 0..112
    int k = threadIdx.x;     // 0..127
    __shared__ float sw[112], sb[112];
    __shared__ int sr[112];
    if (k < 112) { sw[k] = Wn[k]; sb[k] = bn[k]; sr[k] = rankArr[k]; }
    __syncthreads();
    if (k >= OUTC) return;
    float a = 0.f, c = 0.f;
    const float* wcrow = Wc + k * OUTC;   // Wc is [112][112] row-major
    for (int j = 0; j < OUTC; ++j) {
        float w = sw[j];
        bool act = (w == 0.0f) ? (sb[j] > 0.0f)
                               : ((w > 0.0f) ? (sr[j] < s) : (sr[j] >= s));
        if (act) { float wc = wcrow[j]; a += wc * w; c += wc * sb[j]; }
    }
    float w1 = wcat[k * 2 + 1];
    Atab[s * OUTC + k] = w1 * a;
    Ctab[s * OUTC + k] = w1 * (c + bc[k]) + bcat[k] + wcat[k * 2 + 0] * b0[k];
}

// ---------------- Main kernel ----------------
// Each wave: 32 rows (2 MFMA row-tiles of 16) x 112 cols (7 col-tiles), K=256
// in 8 k-tiles of mfma_f32_16x16x32_bf16, 3 products per tile (hh, hl, lh).
// W0 hi/lo fragments come straight from global (L2-hot, 114KB). No main-loop
// barriers; epilogue adds the piecewise-linear node branch from L2 tables.
__global__ __launch_bounds__(256) void NodePredictor_main(
    const float* __restrict__ x, const float* __restrict__ node_info,
    const unsigned short* __restrict__ Wh, const unsigned short* __restrict__ Wl,
    const float* __restrict__ sortedTheta,
    const float* __restrict__ Atab, const float* __restrict__ Ctab,
    float* __restrict__ out)
{
    __shared__ float sTh[128];
    int tid = threadIdx.x;
    if (tid < 128) sTh[tid] = sortedTheta[tid];
    __syncthreads();

    int lane = tid & 63;
    int wv = tid >> 6;
    long tile = (long)blockIdx.x * 4 + wv;
    long base = tile * 32;
    if (base >= NROWS) return;     // 500000 = 32*15625 exactly; guard tail waves
    int l15 = lane & 15;
    int kg  = lane >> 4;

    // --- per-row t and segment (lanes 0..31 each own one of the 32 rows) ---
    float t_own = 0.f; int seg_own = 0;
    if (lane < 32) {
        float t = node_info[base + lane];
        int p = 0;
        #pragma unroll
        for (int st = 64; st > 0; st >>= 1)
            if (sTh[p + st - 1] < t) p += st;   // p = #{theta < t}; pads are +inf
        seg_own = p; t_own = t;
    }
    float tv[2][4]; int sv[2][4];
    #pragma unroll
    for (int rt = 0; rt < 2; ++rt)
        #pragma unroll
        for (int i = 0; i < 4; ++i) {
            int r = rt * 16 + kg * 4 + i;       // D row = (lane>>4)*4 + reg
            tv[rt][i] = __shfl(t_own, r);
            sv[rt][i] = __shfl(seg_own, r);
        }

    f32x4 acc[2][7];
    #pragma unroll
    for (int rt = 0; rt < 2; ++rt)
        #pragma unroll
        for (int ct = 0; ct < 7; ++ct)
            acc[rt][ct] = (f32x4){0.f, 0.f, 0.f, 0.f};

    #pragma unroll 2
    for (int kt = 0; kt < 8; ++kt) {
        int g = kt * 4 + kg;
        // A fragments: row = lane&15, k = kt*32 + (lane>>4)*8 + j
        short8 ah[2], al[2];
        #pragma unroll
        for (int rt = 0; rt < 2; ++rt) {
            const float* xp = x + (base + rt * 16 + l15) * (long)INC + kt * 32 + kg * 8;
            f32x4 v0 = __builtin_nontemporal_load((const f32x4*)xp);
            f32x4 v1 = __builtin_nontemporal_load((const f32x4*)(xp + 4));
            #pragma unroll
            for (int j = 0; j < 8; ++j) {
                float f = (j < 4) ? v0[j] : v1[j - 4];
                unsigned short hi = bf16_rne(f);
                float resid = f - bf16_to_f32(hi);   // exact
                ah[rt][j] = (short)hi;
                al[rt][j] = (short)bf16_rne(resid);
            }
        }
        // B fragments from L2: col = ct*16 + (lane&15), same k-group g
        const short8* Bh = (const short8*)(Wh + (size_t)g * OUTC * 8);
        const short8* Bl = (const short8*)(Wl + (size_t)g * OUTC * 8);
        #pragma unroll
        for (int ct = 0; ct < 7; ++ct) {
            short8 bh = Bh[ct * 16 + l15];
            short8 bl = Bl[ct * 16 + l15];
            #pragma unroll
            for (int rt = 0; rt < 2; ++rt) {
                acc[rt][ct] = __builtin_amdgcn_mfma_f32_16x16x32_bf16(ah[rt], bh, acc[rt][ct], 0, 0, 0);
                acc[rt][ct] = __builtin_amdgcn_mfma_f32_16x16x32_bf16(ah[rt], bl, acc[rt][ct], 0, 0, 0);
                acc[rt][ct] = __builtin_amdgcn_mfma_f32_16x16x32_bf16(al[rt], bh, acc[rt][ct], 0, 0, 0);
            }
        }
    }

    // --- epilogue: out = acc + A[seg]*t + C[seg] ---
    #pragma unroll
    for (int rt = 0; rt < 2; ++rt)
        #pragma unroll
        for (int i = 0; i < 4; ++i) {
            long row = base + rt * 16 + kg * 4 + i;
            float t = tv[rt][i];
            const float* Ar = Atab + sv[rt][i] * OUTC;
            const float* Cr = Ctab + sv[rt][i] * OUTC;
            float* orow = out + row * (long)OUTC;
            #pragma unroll
            for (int ct = 0; ct < 7; ++ct) {
                int col = ct * 16 + l15;
                float v = acc[rt][ct][i] + Ar[col] * t + Cr[col];
                __builtin_nontemporal_store(v, &orow[col]);
            }
        }
}

extern "C" void kernel_launch(void* const* d_in, const int* in_sizes, int n_in,
                              void* d_out, int out_size, void* d_ws, size_t ws_size,
                              hipStream_t stream)
{
    const float* x    = (const float*)d_in[0];
    const float* ni   = (const float*)d_in[1];
    const float* W0   = (const float*)d_in[2];
    const float* b0   = (const float*)d_in[3];
    const float* Wn   = (const float*)d_in[4];
    const float* bn   = (const float*)d_in[5];
    const float* Wc   = (const float*)d_in[6];
    const float* bc   = (const float*)d_in[7];
    const float* wcat = (const float*)d_in[8];
    const float* bcat = (const float*)d_in[9];
    float* out = (float*)d_out;

    char* ws = (char*)d_ws;
    unsigned short* Wh   = (unsigned short*)(ws);              // 57344 B
    unsigned short* Wl   = (unsigned short*)(ws + 57344);      // 57344 B
    float* sTheta        = (float*)(ws + 114688);              // 512 B
    int* rankArr         = (int*)(ws + 115200);                // 512 B
    float* Atab          = (float*)(ws + 115712);              // 50624 B
    float* Ctab          = (float*)(ws + 166336);              // 50624 B -> 216960 total

    prep1<<<8, 256, 0, stream>>>(W0, Wn, bn, wcat, Wh, Wl, sTheta, rankArr);
    prep2<<<113, 128, 0, stream>>>(Wn, bn, Wc, bc, wcat, bcat, b0, rankArr, Atab, Ctab);

    const int tiles = (NROWS + 31) / 32;          // 15625
    const int blocks = (tiles + 3) / 4;           // 3907, 4 waves/block
    NodePredictor_main<<<blocks, 256, 0, stream>>>(x, ni, Wh, Wl, sTheta, Atab, Ctab, out);
}